// Round 6
// baseline (1210.394 us; speedup 1.0000x reference)
//
#include <hip/hip_runtime.h>
#include <hip/hip_bf16.h>
#include <cstdint>

// B=2, T=2048, HID=1024, H=16, DK=DV=64, K(conv)=4. fp32 in/out.
// ws: 4 bf16 planes (32 MB). d_out doubles as scratch: betab fp32 [0,256K),
// xb bf16 plane at [8M,16M) -- both consumed before the final GEMM writes d_out.

using bf16 = __hip_bfloat16;
typedef __bf16 bf16x8 __attribute__((ext_vector_type(8)));
typedef __bf16 bf16x4v __attribute__((ext_vector_type(4)));
typedef float f32x4 __attribute__((ext_vector_type(4)));

__device__ __forceinline__ __bf16 cvt_bf16(float f) {
  __hip_bfloat16 h = (__hip_bfloat16)f;
  return *reinterpret_cast<__bf16*>(&h);
}
__device__ __forceinline__ void async_copy16(const void* g, void* l) {
  __builtin_amdgcn_global_load_lds((const __attribute__((address_space(1))) void*)g,
                                   (__attribute__((address_space(3))) void*)l,
                                   16, 0, 0);
}

// fp32 -> bf16 plane (4M elements)
__global__ __launch_bounds__(256) void cvt_plane_kernel(
    const float* __restrict__ in, bf16* __restrict__ out)
{
  size_t i = ((size_t)blockIdx.x * 256 + threadIdx.x) * 4;
  float4 f = *(const float4*)(in + i);
  bf16x4v t;
  t[0] = cvt_bf16(f.x); t[1] = cvt_bf16(f.y); t[2] = cvt_bf16(f.z); t[3] = cvt_bf16(f.w);
  *(bf16x4v*)((__bf16*)out + i) = t;
}

// C = A * Bt^T. A: MxK bf16 (async global->LDS); Bt: NxK fp32 (cvt at staging).
// MODE 1: sigmoid(acc+bias)->fp32 Cf; 2: raw->bf16 Cb; 3: sigmoid(acc+bias)->bf16 Cb; 4: raw->fp32 Cf
template <int MODE>
__global__ __launch_bounds__(256) void gemm_bt(
    const bf16* __restrict__ A, const float* __restrict__ Bt,
    const float* __restrict__ bias, float* __restrict__ Cf, bf16* __restrict__ Cb,
    int M, int N, int K)
{
  __shared__ __align__(16) __bf16 As[128 * 32];
  __shared__ __align__(16) __bf16 Bs[128 * 32];

  const int tid  = threadIdx.x;
  const int lane = tid & 63;
  const int wave = tid >> 6;
  const int tile_m = blockIdx.y * 128;
  const int tile_n = blockIdx.x * 128;
  const int wm = (wave >> 1) * 64;
  const int wn = (wave & 1) * 64;

  const int srow = lane >> 2;
  const int scol = (lane & 3) * 8;

  f32x4 acc[4][4];
#pragma unroll
  for (int i = 0; i < 4; ++i)
#pragma unroll
    for (int j = 0; j < 4; ++j) acc[i][j] = {0.f, 0.f, 0.f, 0.f};

  for (int k0 = 0; k0 < K; k0 += 32) {
    float4 b0[2], b1[2];
#pragma unroll
    for (int s = 0; s < 2; ++s) {
      int brow = tile_n + s * 64 + wave * 16 + srow;
      if (brow > N - 1) brow = N - 1;             // clamp (beta GEMM: N=16)
      const float* bp = Bt + (size_t)brow * K + k0 + scol;
      b0[s] = *(const float4*)bp;
      b1[s] = *(const float4*)(bp + 4);
    }
    __syncthreads();
#pragma unroll
    for (int s = 0; s < 2; ++s) {
      int arow = tile_m + s * 64 + wave * 16 + srow;
      async_copy16((const __bf16*)A + (size_t)arow * K + k0 + scol,
                   &As[(s * 64 + wave * 16 + srow) * 32 + scol]);
      bf16x8 u;
      u[0] = cvt_bf16(b0[s].x); u[1] = cvt_bf16(b0[s].y);
      u[2] = cvt_bf16(b0[s].z); u[3] = cvt_bf16(b0[s].w);
      u[4] = cvt_bf16(b1[s].x); u[5] = cvt_bf16(b1[s].y);
      u[6] = cvt_bf16(b1[s].z); u[7] = cvt_bf16(b1[s].w);
      *(bf16x8*)&Bs[(s * 64 + wave * 16 + srow) * 32 + scol] = u;
    }
    __syncthreads();

    bf16x8 af[4], bfr[4];
#pragma unroll
    for (int i = 0; i < 4; ++i)
      af[i] = *(const bf16x8*)&As[(wm + i * 16 + (lane & 15)) * 32 + (lane >> 4) * 8];
#pragma unroll
    for (int j = 0; j < 4; ++j)
      bfr[j] = *(const bf16x8*)&Bs[(wn + j * 16 + (lane & 15)) * 32 + (lane >> 4) * 8];

#pragma unroll
    for (int i = 0; i < 4; ++i)
#pragma unroll
      for (int j = 0; j < 4; ++j)
        acc[i][j] = __builtin_amdgcn_mfma_f32_16x16x32_bf16(af[i], bfr[j], acc[i][j], 0, 0, 0);
  }

  // C/D layout (m89-verified): col = lane&15, row = (lane>>4)*4 + reg
#pragma unroll
  for (int i = 0; i < 4; ++i) {
#pragma unroll
    for (int j = 0; j < 4; ++j) {
#pragma unroll
      for (int r = 0; r < 4; ++r) {
        int gm = tile_m + wm + i * 16 + (lane >> 4) * 4 + r;
        int gn = tile_n + wn + j * 16 + (lane & 15);
        if (gn < N) {
          float val = acc[i][j][r];
          if (MODE == 1 || MODE == 3) {
            float bv = bias ? bias[gn] : 0.f;
            val = 1.f / (1.f + __expf(-(val + bv)));
          }
          if (MODE == 1 || MODE == 4) Cf[(size_t)gm * N + gn] = val;
          else                        Cb[(size_t)gm * N + gn] = (bf16)val;
        }
      }
    }
  }
}

// causal depthwise conv K=4 + bias + SiLU (+scale). z: [B*T,1024] bf16 plane.
__global__ __launch_bounds__(256) void conv_silu_kernel(
    const bf16* __restrict__ z, const float* __restrict__ w,
    const float* __restrict__ bias, bf16* __restrict__ out, float scale)
{
  int idx = blockIdx.x * 256 + threadIdx.x;
  int c = idx & 1023;
  int m = idx >> 10;
  int t = m & 2047;
  float w0 = w[c * 4 + 0], w1 = w[c * 4 + 1], w2 = w[c * 4 + 2], w3 = w[c * 4 + 3];
  float acc = bias[c] + (float)z[idx] * w3;
  if (t >= 1) acc += (float)z[idx - 1024] * w2;
  if (t >= 2) acc += (float)z[idx - 2048] * w1;
  if (t >= 3) acc += (float)z[idx - 3072] * w0;
  float s = acc / (1.f + __expf(-acc));
  out[idx] = (bf16)(s * scale);
}

// delta-rule scan: 1 block/(b,h); thread (r=tid>>2, c0=(tid&3)*16) holds
// S[r][c0..c0+15] fp32. bf16 LDS staging via async global->LDS (16 steps/chunk,
// double buffered, 1 barrier/chunk); 2-deep register pipeline over steps;
// o batched through LDS -> 1 coalesced store/thread/chunk. o aliases v
// (chunk c writes rows c*16..c*16+15 after they are consumed; staging of chunk
// c+1 reads strictly later rows).
__global__ __launch_bounds__(256) void scan_kernel(
    const bf16* __restrict__ q, const bf16* __restrict__ k,
    const bf16* v, const bf16* __restrict__ a,
    const float* __restrict__ betab, bf16* o)
{
  const int bh = blockIdx.x;
  const int b = bh >> 4, h = bh & 15;
  const int tid = threadIdx.x;
  const int lane = tid & 63;
  const int seg = tid >> 6;
  const int r = tid >> 2;
  const int c0 = (tid & 3) * 16;    // bf16 element offset within 64-col row

  __shared__ __align__(16) __bf16 sq[2][16][64];   // 4 KB each
  __shared__ __align__(16) __bf16 sk[2][16][64];
  __shared__ __align__(16) __bf16 sv[2][16][64];
  __shared__ __align__(16) __bf16 sa[2][16][64];
  __shared__ __align__(16) __bf16 so[2][16][64];
  __shared__ float sbeta[2048];                    // 8 KB  (total 28 KB)

  for (int t = tid; t < 2048; t += 256)
    sbeta[t] = betab[((size_t)b * 2048 + t) * 16 + h];

  const size_t base = (size_t)b * 2048 * 1024 + h * 64;  // plane element offset

  // this wave's staging plane (q->sq, k->sk, v->sv, a->sa)
  const __bf16* src = (seg == 0) ? (const __bf16*)q : (seg == 1) ? (const __bf16*)k
                    : (seg == 2) ? (const __bf16*)v : (const __bf16*)a;
  __bf16* dstp = (seg == 0) ? &sq[0][0][0] : (seg == 1) ? &sk[0][0][0]
               : (seg == 2) ? &sv[0][0][0] : &sa[0][0][0];
  const int lrow = lane >> 3;          // 0..7
  const int lcol = (lane & 7) * 8;     // 0..56

  // stage chunk 0 -> buf 0 (LDS dest == waveBase + lane*16: verified layout)
#pragma unroll
  for (int it = 0; it < 2; ++it) {
    int st = it * 8 + lrow;
    async_copy16(src + base + (size_t)st * 1024 + lcol,
                 dstp + it * 512 + (size_t)lane * 8);
  }

  float S[16];
#pragma unroll
  for (int j = 0; j < 16; ++j) S[j] = 0.f;
  __syncthreads();   // drains async (vmcnt) + beta staging

  for (int c = 0; c < 128; ++c) {
    const int buf = c & 1;
    if (c + 1 < 128) {   // stage chunk c+1 into buf^1 (overlaps 16 steps below)
      int t0n = (c + 1) * 16;
#pragma unroll
      for (int it = 0; it < 2; ++it) {
        int st = it * 8 + lrow;
        async_copy16(src + base + (size_t)(t0n + st) * 1024 + lcol,
                     dstp + (buf ^ 1) * 1024 + it * 512 + (size_t)lane * 8);
      }
    }

    // register pipeline: set p holds step i, set p^1 gets step i+1
    bf16x8 kk8[2][2], qq8[2][2];
    float vr2[2], ar2[2], bt2[2];
    kk8[0][0] = *(const bf16x8*)&sk[buf][0][c0];
    kk8[0][1] = *(const bf16x8*)&sk[buf][0][c0 + 8];
    qq8[0][0] = *(const bf16x8*)&sq[buf][0][c0];
    qq8[0][1] = *(const bf16x8*)&sq[buf][0][c0 + 8];
    vr2[0] = (float)sv[buf][0][r];
    ar2[0] = (float)sa[buf][0][r];
    bt2[0] = sbeta[c * 16];

#pragma unroll
    for (int i = 0; i < 16; ++i) {
      const int p = i & 1;
      if (i + 1 < 16) {   // issue next step's LDS reads (hidden under compute)
        kk8[p ^ 1][0] = *(const bf16x8*)&sk[buf][i + 1][c0];
        kk8[p ^ 1][1] = *(const bf16x8*)&sk[buf][i + 1][c0 + 8];
        qq8[p ^ 1][0] = *(const bf16x8*)&sq[buf][i + 1][c0];
        qq8[p ^ 1][1] = *(const bf16x8*)&sq[buf][i + 1][c0 + 8];
        vr2[p ^ 1] = (float)sv[buf][i + 1][r];
        ar2[p ^ 1] = (float)sa[buf][i + 1][r];
        bt2[p ^ 1] = sbeta[c * 16 + i + 1];
      }

      float kf[16], qf[16];
#pragma unroll
      for (int jj = 0; jj < 2; ++jj)
#pragma unroll
        for (int j = 0; j < 8; ++j) {
          kf[jj * 8 + j] = (float)kk8[p][jj][j];
          qf[jj * 8 + j] = (float)qq8[p][jj][j];
        }
      const float vr = vr2[p], ar = ar2[p], bt = bt2[p];

      float d0 = 0.f, d1 = 0.f, d2 = 0.f, d3 = 0.f;
#pragma unroll
      for (int j = 0; j < 4; ++j) {
        d0 += S[j] * kf[j];         d1 += S[4 + j] * kf[4 + j];
        d2 += S[8 + j] * kf[8 + j]; d3 += S[12 + j] * kf[12 + j];
      }
      float dot = (d0 + d1) + (d2 + d3);
      dot += __shfl_xor(dot, 1);
      dot += __shfl_xor(dot, 2);
      float cc = bt * (dot - vr);           // beta * err[r]

      float o0 = 0.f, o1 = 0.f, o2 = 0.f, o3 = 0.f;
#pragma unroll
      for (int j = 0; j < 4; ++j) {
        S[j]      = ar * S[j]      - cc * kf[j];       o0 += S[j]      * qf[j];
        S[4 + j]  = ar * S[4 + j]  - cc * kf[4 + j];   o1 += S[4 + j]  * qf[4 + j];
        S[8 + j]  = ar * S[8 + j]  - cc * kf[8 + j];   o2 += S[8 + j]  * qf[8 + j];
        S[12 + j] = ar * S[12 + j] - cc * kf[12 + j];  o3 += S[12 + j] * qf[12 + j];
      }
      float od = (o0 + o1) + (o2 + o3);
      od += __shfl_xor(od, 1);
      od += __shfl_xor(od, 2);
      if ((tid & 3) == 0) so[buf][i][r] = (__bf16)od;
    }

    __syncthreads();   // so[buf] visible; buf^1 staged (vmcnt drained)

    {  // coalesced store of chunk c's outputs: 8 B per thread
      int i2 = tid >> 4;
      int rr = (tid & 15) * 4;
      bf16x4v val = *(const bf16x4v*)&so[buf][i2][rr];
      *(bf16x4v*)((__bf16*)o + base + (size_t)(c * 16 + i2) * 1024 + rr) = val;
    }
  }
}

// LayerNorm over DV=64 per (b,t,h) row, *ln_w+ln_b, *gate -> bf16
__global__ __launch_bounds__(256) void ln_gate_kernel(
    const bf16* __restrict__ o, const bf16* __restrict__ g,
    const float* __restrict__ lnw, const float* __restrict__ lnb,
    bf16* __restrict__ out)
{
  int row = blockIdx.x * 4 + (threadIdx.x >> 6);
  int lane = threadIdx.x & 63;
  size_t idx = (size_t)row * 64 + lane;
  float xv = (float)o[idx];
  float mu = xv;
#pragma unroll
  for (int s = 1; s < 64; s <<= 1) mu += __shfl_xor(mu, s);
  mu *= (1.f / 64.f);
  float d = xv - mu;
  float vv = d * d;
#pragma unroll
  for (int s = 1; s < 64; s <<= 1) vv += __shfl_xor(vv, s);
  vv *= (1.f / 64.f);
  float y = d * rsqrtf(vv + 1e-5f) * lnw[lane] + lnb[lane];
  y *= (float)g[idx];
  out[idx] = (bf16)y;
}

extern "C" void kernel_launch(void* const* d_in, const int* in_sizes, int n_in,
                              void* d_out, int out_size, void* d_ws, size_t ws_size,
                              hipStream_t stream)
{
  const float* x   = (const float*)d_in[0];
  const float* Wq  = (const float*)d_in[1];
  const float* Wk  = (const float*)d_in[2];
  const float* Wv  = (const float*)d_in[3];
  const float* Wa  = (const float*)d_in[4];
  const float* ba  = (const float*)d_in[5];
  const float* Wb  = (const float*)d_in[6];
  const float* bb  = (const float*)d_in[7];
  const float* Wg  = (const float*)d_in[8];
  const float* Wo  = (const float*)d_in[9];
  const float* qcw = (const float*)d_in[10];
  const float* qcb = (const float*)d_in[11];
  const float* kcw = (const float*)d_in[12];
  const float* kcb = (const float*)d_in[13];
  const float* vcw = (const float*)d_in[14];
  const float* vcb = (const float*)d_in[15];
  const float* lnw = (const float*)d_in[16];
  const float* lnb = (const float*)d_in[17];

  const int M = 4096, HID = 1024;
  const size_t PLANE = (size_t)M * HID;
  const size_t PB = PLANE * sizeof(bf16);          // 8 MB bf16 plane

  char* ws = (char*)d_ws;
  bf16* P  = (bf16*)(ws);            // z-plane x3, then a-gate
  bf16* qb = (bf16*)(ws + PB);       // q, then g-gate
  bf16* kb = (bf16*)(ws + 2 * PB);   // k, then normalized*gated o
  bf16* vb = (bf16*)(ws + 3 * PB);   // v, then scan output (in-place)

  float* outf  = (float*)d_out;
  float* betab = outf;                                    // [0, 256 KB)
  bf16*  xb    = (bf16*)((char*)d_out + 8 * 1024 * 1024); // [8M, 16M)

  dim3 blk(256);
  dim3 g8(8, 32);
  int nconv = (int)(PLANE / 256);

  cvt_plane_kernel<<<(int)(PLANE / 1024), blk, 0, stream>>>(x, xb);

  gemm_bt<2><<<g8, blk, 0, stream>>>(xb, Wq, nullptr, nullptr, P, M, HID, HID);
  conv_silu_kernel<<<nconv, blk, 0, stream>>>(P, qcw, qcb, qb, 1.f);

  gemm_bt<2><<<g8, blk, 0, stream>>>(xb, Wk, nullptr, nullptr, P, M, HID, HID);
  conv_silu_kernel<<<nconv, blk, 0, stream>>>(P, kcw, kcb, kb, 0.125f);  // * DK^-0.5

  gemm_bt<2><<<g8, blk, 0, stream>>>(xb, Wv, nullptr, nullptr, P, M, HID, HID);
  conv_silu_kernel<<<nconv, blk, 0, stream>>>(P, vcw, vcb, vb, 1.f);

  gemm_bt<3><<<g8, blk, 0, stream>>>(xb, Wa, ba, nullptr, P, M, HID, HID);
  gemm_bt<1><<<dim3(1, 32), blk, 0, stream>>>(xb, Wb, bb, betab, nullptr, M, 16, HID);

  scan_kernel<<<32, blk, 0, stream>>>(qb, kb, vb, P, betab, vb);

  gemm_bt<3><<<g8, blk, 0, stream>>>(xb, Wg, nullptr, nullptr, qb, M, HID, HID);

  ln_gate_kernel<<<M * 16 / 4, blk, 0, stream>>>(vb, qb, lnw, lnb, kb);

  gemm_bt<4><<<g8, blk, 0, stream>>>(kb, Wo, nullptr, outf, nullptr, M, HID, HID);
}

// Round 7
// 869.334 us; speedup vs baseline: 1.3923x; 1.3923x over previous
//
#include <hip/hip_runtime.h>
#include <hip/hip_bf16.h>
#include <cstdint>

// B=2, T=2048, HID=1024, H=16, DK=DV=64, K(conv)=4. fp32 in/out.
// ws: 4 bf16 planes (32 MB) [+ optional 5th plane xb if ws_size >= 40 MB].
// d_out as scratch: betab fp32 transposed [16][4096] at [0,256K); scan output
// plane ob bf16 at [8M,16M). Both dead before the final GEMM writes d_out.
// Scan: 128 blocks x 64 thr (1 wave/CU), DPP quad reductions (no ds_bpermute
// in the dependency chain), f32x2 packed math, register-mediated staging.

using bf16 = __hip_bfloat16;
typedef __bf16 bf16x8 __attribute__((ext_vector_type(8)));
typedef __bf16 bf16x4v __attribute__((ext_vector_type(4)));
typedef float f32x4 __attribute__((ext_vector_type(4)));
typedef float f32x2 __attribute__((ext_vector_type(2)));
typedef unsigned int u32x4 __attribute__((ext_vector_type(4)));

__device__ __forceinline__ __bf16 cvt_bf16(float f) {
  __hip_bfloat16 h = (__hip_bfloat16)f;
  return *reinterpret_cast<__bf16*>(&h);
}
__device__ __forceinline__ void async_copy16(const void* g, void* l) {
  __builtin_amdgcn_global_load_lds((const __attribute__((address_space(1))) void*)g,
                                   (__attribute__((address_space(3))) void*)l,
                                   16, 0, 0);
}
__device__ __forceinline__ float bcf(unsigned int u) { return __builtin_bit_cast(float, u); }
// quad-local butterfly adds via DPP (VALU-routed; replaces ds_bpermute shuffles)
__device__ __forceinline__ float dpp_add_xor1(float x) {
  int y = __builtin_amdgcn_update_dpp(0, __builtin_bit_cast(int, x), 0xB1, 0xF, 0xF, true);
  return x + __builtin_bit_cast(float, y);
}
__device__ __forceinline__ float dpp_add_xor2(float x) {
  int y = __builtin_amdgcn_update_dpp(0, __builtin_bit_cast(int, x), 0x4E, 0xF, 0xF, true);
  return x + __builtin_bit_cast(float, y);
}

// fp32 -> bf16 plane (4M elements)
__global__ __launch_bounds__(256) void cvt_plane_kernel(
    const float* __restrict__ in, bf16* __restrict__ out)
{
  size_t i = ((size_t)blockIdx.x * 256 + threadIdx.x) * 4;
  float4 f = *(const float4*)(in + i);
  bf16x4v t;
  t[0] = cvt_bf16(f.x); t[1] = cvt_bf16(f.y); t[2] = cvt_bf16(f.z); t[3] = cvt_bf16(f.w);
  *(bf16x4v*)((__bf16*)out + i) = t;
}

// C = A * Bt^T. A: MxK (bf16 async-staged unless A_FP32); Bt: NxK fp32.
// MODE 2: raw->bf16; 3: sigmoid(acc+bias)->bf16; 4: raw->fp32; 5: sigmoid(acc+bias)->fp32 TRANSPOSED
template <int MODE, bool A_FP32>
__global__ __launch_bounds__(256) void gemm_bt(
    const void* __restrict__ Av, const float* __restrict__ Bt,
    const float* __restrict__ bias, float* __restrict__ Cf, bf16* __restrict__ Cb,
    int M, int N, int K)
{
  __shared__ __align__(16) __bf16 As[128 * 32];
  __shared__ __align__(16) __bf16 Bs[128 * 32];

  const int tid  = threadIdx.x;
  const int lane = tid & 63;
  const int wave = tid >> 6;
  const int tile_m = blockIdx.y * 128;
  const int tile_n = blockIdx.x * 128;
  const int wm = (wave >> 1) * 64;
  const int wn = (wave & 1) * 64;

  const int srow = lane >> 2;
  const int scol = (lane & 3) * 8;

  f32x4 acc[4][4];
#pragma unroll
  for (int i = 0; i < 4; ++i)
#pragma unroll
    for (int j = 0; j < 4; ++j) acc[i][j] = {0.f, 0.f, 0.f, 0.f};

  for (int k0 = 0; k0 < K; k0 += 32) {
    float4 b0[2], b1[2], a0[2], a1[2];
#pragma unroll
    for (int s = 0; s < 2; ++s) {
      int brow = tile_n + s * 64 + wave * 16 + srow;
      if (brow > N - 1) brow = N - 1;             // clamp (beta GEMM: N=16)
      const float* bp = Bt + (size_t)brow * K + k0 + scol;
      b0[s] = *(const float4*)bp;
      b1[s] = *(const float4*)(bp + 4);
      if (A_FP32) {
        int arow = tile_m + s * 64 + wave * 16 + srow;
        const float* ap = (const float*)Av + (size_t)arow * K + k0 + scol;
        a0[s] = *(const float4*)ap;
        a1[s] = *(const float4*)(ap + 4);
      }
    }
    __syncthreads();
#pragma unroll
    for (int s = 0; s < 2; ++s) {
      if (!A_FP32) {
        int arow = tile_m + s * 64 + wave * 16 + srow;
        async_copy16((const __bf16*)Av + (size_t)arow * K + k0 + scol,
                     &As[(s * 64 + wave * 16 + srow) * 32 + scol]);
      } else {
        bf16x8 ua;
        ua[0] = cvt_bf16(a0[s].x); ua[1] = cvt_bf16(a0[s].y);
        ua[2] = cvt_bf16(a0[s].z); ua[3] = cvt_bf16(a0[s].w);
        ua[4] = cvt_bf16(a1[s].x); ua[5] = cvt_bf16(a1[s].y);
        ua[6] = cvt_bf16(a1[s].z); ua[7] = cvt_bf16(a1[s].w);
        *(bf16x8*)&As[(s * 64 + wave * 16 + srow) * 32 + scol] = ua;
      }
      bf16x8 u;
      u[0] = cvt_bf16(b0[s].x); u[1] = cvt_bf16(b0[s].y);
      u[2] = cvt_bf16(b0[s].z); u[3] = cvt_bf16(b0[s].w);
      u[4] = cvt_bf16(b1[s].x); u[5] = cvt_bf16(b1[s].y);
      u[6] = cvt_bf16(b1[s].z); u[7] = cvt_bf16(b1[s].w);
      *(bf16x8*)&Bs[(s * 64 + wave * 16 + srow) * 32 + scol] = u;
    }
    __syncthreads();

    bf16x8 af[4], bfr[4];
#pragma unroll
    for (int i = 0; i < 4; ++i)
      af[i] = *(const bf16x8*)&As[(wm + i * 16 + (lane & 15)) * 32 + (lane >> 4) * 8];
#pragma unroll
    for (int j = 0; j < 4; ++j)
      bfr[j] = *(const bf16x8*)&Bs[(wn + j * 16 + (lane & 15)) * 32 + (lane >> 4) * 8];

#pragma unroll
    for (int i = 0; i < 4; ++i)
#pragma unroll
      for (int j = 0; j < 4; ++j)
        acc[i][j] = __builtin_amdgcn_mfma_f32_16x16x32_bf16(af[i], bfr[j], acc[i][j], 0, 0, 0);
  }

  // C/D layout (m89-verified): col = lane&15, row = (lane>>4)*4 + reg
#pragma unroll
  for (int i = 0; i < 4; ++i) {
#pragma unroll
    for (int j = 0; j < 4; ++j) {
#pragma unroll
      for (int r = 0; r < 4; ++r) {
        int gm = tile_m + wm + i * 16 + (lane >> 4) * 4 + r;
        int gn = tile_n + wn + j * 16 + (lane & 15);
        if (gn < N) {
          float val = acc[i][j][r];
          if (MODE == 3 || MODE == 5) {
            float bv = bias ? bias[gn] : 0.f;
            val = 1.f / (1.f + __expf(-(val + bv)));
          }
          if (MODE == 4)      Cf[(size_t)gm * N + gn] = val;
          else if (MODE == 5) Cf[(size_t)gn * M + gm] = val;   // transposed
          else                Cb[(size_t)gm * N + gn] = (bf16)val;
        }
      }
    }
  }
}

// causal depthwise conv K=4 + bias + SiLU (+scale). z: [B*T,1024] bf16 plane.
__global__ __launch_bounds__(256) void conv_silu_kernel(
    const bf16* __restrict__ z, const float* __restrict__ w,
    const float* __restrict__ bias, bf16* __restrict__ out, float scale)
{
  int idx = blockIdx.x * 256 + threadIdx.x;
  int c = idx & 1023;
  int m = idx >> 10;
  int t = m & 2047;
  float w0 = w[c * 4 + 0], w1 = w[c * 4 + 1], w2 = w[c * 4 + 2], w3 = w[c * 4 + 3];
  float acc = bias[c] + (float)z[idx] * w3;
  if (t >= 1) acc += (float)z[idx - 1024] * w2;
  if (t >= 2) acc += (float)z[idx - 2048] * w1;
  if (t >= 3) acc += (float)z[idx - 3072] * w0;
  float s = acc / (1.f + __expf(-acc));
  out[idx] = (bf16)(s * scale);
}

// delta-rule scan: 128 blocks (b,h,qd) x 64 threads; block owns DV rows
// [qd*16, qd*16+16). Thread (rl=tid>>2, seg=tid&3) holds S[rl][seg*16..+16)
// as f32x2[8]. 16-step chunks, double-buffered LDS, register staging,
// DPP quad reductions, 1-step register pipeline.
__global__ __launch_bounds__(64) void scan_kernel(
    const bf16* __restrict__ q, const bf16* __restrict__ k,
    const bf16* __restrict__ v, const bf16* __restrict__ a,
    const float* __restrict__ betab, bf16* __restrict__ o)
{
  const int blk = blockIdx.x;
  const int qd = blk & 3, h = (blk >> 2) & 15, b = blk >> 6;
  const int tid = threadIdx.x;
  const int lane = tid;              // 64-thread block = one wave
  const int rl = tid >> 2;           // 0..15 local row
  const int seg = tid & 3;
  const int c0 = seg * 16;

  __shared__ __align__(16) __bf16 sk[2][16][64];     // 4 KB
  __shared__ __align__(16) __bf16 sq[2][16][64];     // 4 KB
  __shared__ __align__(16) __bf16 sva[2][2][16][16]; // 2 KB [buf][v/a][step][row]
  __shared__ float sbeta[2048];                      // 8 KB

  {  // beta: transposed layout [h][4096] -> contiguous
    const float* bp = betab + (size_t)h * 4096 + b * 2048;
    for (int t = tid; t < 2048; t += 64) sbeta[t] = bp[t];
  }

  const size_t bqh = (size_t)b * 2048 * 1024 + h * 64;   // k/q/o base
  const size_t bva = bqh + qd * 16;                      // v/a slice base
  const __bf16* kp = (const __bf16*)k;
  const __bf16* qp = (const __bf16*)q;
  const __bf16* vp = (const __bf16*)v;
  const __bf16* ap = (const __bf16*)a;

  // ---- register-mediated staging (global->reg early, reg->LDS late) ----
  const int g_st  = lane >> 3;         // 0..7  (step within 8-step group)
  const int g_cg  = (lane & 7) * 8;    // col group for k/q
  const int va_vh = lane >> 5;         // 0: v, 1: a
  const int va_st = (lane & 31) >> 1;  // 0..15 step
  const int va_pt = (lane & 1) * 8;    // row part

  bf16x8 pk[2], pq[2], pva;
  auto fetch = [&](int t0) {
#pragma unroll
    for (int j = 0; j < 2; ++j) {
      int st = t0 + j * 8 + g_st;
      pk[j] = *(const bf16x8*)(kp + bqh + (size_t)st * 1024 + g_cg);
      pq[j] = *(const bf16x8*)(qp + bqh + (size_t)st * 1024 + g_cg);
    }
    const __bf16* sva_src = va_vh ? ap : vp;
    pva = *(const bf16x8*)(sva_src + bva + (size_t)(t0 + va_st) * 1024 + va_pt);
  };
  auto commit = [&](int cbuf) {
#pragma unroll
    for (int j = 0; j < 2; ++j) {
      *(bf16x8*)(&sk[cbuf][j * 8][0] + (size_t)lane * 8) = pk[j];
      *(bf16x8*)(&sq[cbuf][j * 8][0] + (size_t)lane * 8) = pq[j];
    }
    *(bf16x8*)(&sva[cbuf][0][0][0] + (size_t)lane * 8) = pva;
  };

  fetch(0);
  commit(0);

  f32x2 S2[8];
#pragma unroll
  for (int j = 0; j < 8; ++j) S2[j] = {0.f, 0.f};
  __syncthreads();

  for (int c = 0; c < 128; ++c) {
    const int buf = c & 1;
    const bool hasNext = (c + 1 < 128);
    if (hasNext) fetch((c + 1) * 16);   // global loads in flight during compute

    // register pipeline
    bf16x8 kk8[2][2], qq8[2][2];
    float vr2[2], ar2[2], bt2[2];
    kk8[0][0] = *(const bf16x8*)&sk[buf][0][c0];
    kk8[0][1] = *(const bf16x8*)&sk[buf][0][c0 + 8];
    qq8[0][0] = *(const bf16x8*)&sq[buf][0][c0];
    qq8[0][1] = *(const bf16x8*)&sq[buf][0][c0 + 8];
    vr2[0] = (float)sva[buf][0][0][rl];
    ar2[0] = (float)sva[buf][1][0][rl];
    bt2[0] = sbeta[c * 16];

#pragma unroll
    for (int i = 0; i < 16; ++i) {
      const int p = i & 1;
      if (i + 1 < 16) {
        kk8[p ^ 1][0] = *(const bf16x8*)&sk[buf][i + 1][c0];
        kk8[p ^ 1][1] = *(const bf16x8*)&sk[buf][i + 1][c0 + 8];
        qq8[p ^ 1][0] = *(const bf16x8*)&sq[buf][i + 1][c0];
        qq8[p ^ 1][1] = *(const bf16x8*)&sq[buf][i + 1][c0 + 8];
        vr2[p ^ 1] = (float)sva[buf][0][i + 1][rl];
        ar2[p ^ 1] = (float)sva[buf][1][i + 1][rl];
        bt2[p ^ 1] = sbeta[c * 16 + i + 1];
      }

      // unpack bf16 pairs -> f32x2 (shift/mask, 1 inst per element)
      u32x4 kd0 = __builtin_bit_cast(u32x4, kk8[p][0]);
      u32x4 kd1 = __builtin_bit_cast(u32x4, kk8[p][1]);
      u32x4 qd0 = __builtin_bit_cast(u32x4, qq8[p][0]);
      u32x4 qd1 = __builtin_bit_cast(u32x4, qq8[p][1]);
      f32x2 k2[8], q2[8];
#pragma unroll
      for (int j = 0; j < 4; ++j) {
        k2[j]     = {bcf(kd0[j] << 16), bcf(kd0[j] & 0xffff0000u)};
        k2[4 + j] = {bcf(kd1[j] << 16), bcf(kd1[j] & 0xffff0000u)};
        q2[j]     = {bcf(qd0[j] << 16), bcf(qd0[j] & 0xffff0000u)};
        q2[4 + j] = {bcf(qd1[j] << 16), bcf(qd1[j] & 0xffff0000u)};
      }
      const float vr = vr2[p], ar = ar2[p], bt = bt2[p];

      f32x2 dd0 = S2[0] * k2[0], dd1 = S2[1] * k2[1];
      f32x2 dd2 = S2[2] * k2[2], dd3 = S2[3] * k2[3];
      dd0 += S2[4] * k2[4]; dd1 += S2[5] * k2[5];
      dd2 += S2[6] * k2[6]; dd3 += S2[7] * k2[7];
      f32x2 de = (dd0 + dd1) + (dd2 + dd3);
      float dot = de[0] + de[1];
      dot = dpp_add_xor1(dot);
      dot = dpp_add_xor2(dot);                 // full row dot across quad
      float cc = bt * (dot - vr);              // beta * err[row]

      const f32x2 cc2 = {cc, cc}, arv = {ar, ar};
      f32x2 oo0, oo1, oo2, oo3;
      {
        f32x2 t0 = cc2 * k2[0]; S2[0] = arv * S2[0] - t0; oo0 = S2[0] * q2[0];
        f32x2 t1 = cc2 * k2[1]; S2[1] = arv * S2[1] - t1; oo1 = S2[1] * q2[1];
        f32x2 t2 = cc2 * k2[2]; S2[2] = arv * S2[2] - t2; oo2 = S2[2] * q2[2];
        f32x2 t3 = cc2 * k2[3]; S2[3] = arv * S2[3] - t3; oo3 = S2[3] * q2[3];
        f32x2 t4 = cc2 * k2[4]; S2[4] = arv * S2[4] - t4; oo0 += S2[4] * q2[4];
        f32x2 t5 = cc2 * k2[5]; S2[5] = arv * S2[5] - t5; oo1 += S2[5] * q2[5];
        f32x2 t6 = cc2 * k2[6]; S2[6] = arv * S2[6] - t6; oo2 += S2[6] * q2[6];
        f32x2 t7 = cc2 * k2[7]; S2[7] = arv * S2[7] - t7; oo3 += S2[7] * q2[7];
      }
      f32x2 oe = (oo0 + oo1) + (oo2 + oo3);
      float od = oe[0] + oe[1];
      od = dpp_add_xor1(od);
      od = dpp_add_xor2(od);
      if (seg == 0)
        *((__bf16*)o + bqh + (size_t)(c * 16 + i) * 1024 + qd * 16 + rl) = cvt_bf16(od);
    }

    if (hasNext) commit(buf ^ 1);   // loads completed during the 16 steps
    __syncthreads();
  }
}

// LayerNorm over DV=64 per (b,t,h) row, *ln_w+ln_b, *gate -> bf16
__global__ __launch_bounds__(256) void ln_gate_kernel(
    const bf16* __restrict__ o, const bf16* __restrict__ g,
    const float* __restrict__ lnw, const float* __restrict__ lnb,
    bf16* __restrict__ out)
{
  int row = blockIdx.x * 4 + (threadIdx.x >> 6);
  int lane = threadIdx.x & 63;
  size_t idx = (size_t)row * 64 + lane;
  float xv = (float)o[idx];
  float mu = xv;
#pragma unroll
  for (int s = 1; s < 64; s <<= 1) mu += __shfl_xor(mu, s);
  mu *= (1.f / 64.f);
  float d = xv - mu;
  float vv = d * d;
#pragma unroll
  for (int s = 1; s < 64; s <<= 1) vv += __shfl_xor(vv, s);
  vv *= (1.f / 64.f);
  float y = d * rsqrtf(vv + 1e-5f) * lnw[lane] + lnb[lane];
  y *= (float)g[idx];
  out[idx] = (bf16)y;
}

extern "C" void kernel_launch(void* const* d_in, const int* in_sizes, int n_in,
                              void* d_out, int out_size, void* d_ws, size_t ws_size,
                              hipStream_t stream)
{
  const float* x   = (const float*)d_in[0];
  const float* Wq  = (const float*)d_in[1];
  const float* Wk  = (const float*)d_in[2];
  const float* Wv  = (const float*)d_in[3];
  const float* Wa  = (const float*)d_in[4];
  const float* ba  = (const float*)d_in[5];
  const float* Wb  = (const float*)d_in[6];
  const float* bb  = (const float*)d_in[7];
  const float* Wg  = (const float*)d_in[8];
  const float* Wo  = (const float*)d_in[9];
  const float* qcw = (const float*)d_in[10];
  const float* qcb = (const float*)d_in[11];
  const float* kcw = (const float*)d_in[12];
  const float* kcb = (const float*)d_in[13];
  const float* vcw = (const float*)d_in[14];
  const float* vcb = (const float*)d_in[15];
  const float* lnw = (const float*)d_in[16];
  const float* lnb = (const float*)d_in[17];

  const int M = 4096, HID = 1024;
  const size_t PLANE = (size_t)M * HID;
  const size_t PB = PLANE * sizeof(bf16);          // 8 MB bf16 plane

  char* ws = (char*)d_ws;
  bf16* P  = (bf16*)(ws);            // z-plane x3, then a-gate
  bf16* qb = (bf16*)(ws + PB);       // q, then g-gate
  bf16* kb = (bf16*)(ws + 2 * PB);   // k, then normalized*gated o
  bf16* vb = (bf16*)(ws + 3 * PB);   // v

  // d_out scratch: betab transposed fp32 [16][4096] at [0,256K); ob at [8M,16M)
  float* outf  = (float*)d_out;
  float* betab = outf;
  bf16*  ob    = (bf16*)((char*)d_out + 8 * 1024 * 1024);

  const bool rich = (ws_size >= 5 * PB + 1024);
  bf16* xb = rich ? (bf16*)(ws + 4 * PB) : nullptr;

  dim3 blk(256);
  dim3 g8(8, 32);
  int nconv = (int)(PLANE / 256);

  if (rich) {
    cvt_plane_kernel<<<(int)(PLANE / 1024), blk, 0, stream>>>(x, xb);
    gemm_bt<2, false><<<g8, blk, 0, stream>>>(xb, Wq, nullptr, nullptr, P, M, HID, HID);
    conv_silu_kernel<<<nconv, blk, 0, stream>>>(P, qcw, qcb, qb, 1.f);
    gemm_bt<2, false><<<g8, blk, 0, stream>>>(xb, Wk, nullptr, nullptr, P, M, HID, HID);
    conv_silu_kernel<<<nconv, blk, 0, stream>>>(P, kcw, kcb, kb, 0.125f);
    gemm_bt<2, false><<<g8, blk, 0, stream>>>(xb, Wv, nullptr, nullptr, P, M, HID, HID);
    conv_silu_kernel<<<nconv, blk, 0, stream>>>(P, vcw, vcb, vb, 1.f);
    gemm_bt<3, false><<<g8, blk, 0, stream>>>(xb, Wa, ba, nullptr, P, M, HID, HID);
    gemm_bt<5, false><<<dim3(1, 32), blk, 0, stream>>>(xb, Wb, bb, betab, nullptr, M, 16, HID);
    scan_kernel<<<128, dim3(64), 0, stream>>>(qb, kb, vb, P, betab, ob);
    gemm_bt<3, false><<<g8, blk, 0, stream>>>(xb, Wg, nullptr, nullptr, qb, M, HID, HID);
    ln_gate_kernel<<<M * 16 / 4, blk, 0, stream>>>(ob, qb, lnw, lnb, kb);
  } else {
    gemm_bt<2, true><<<g8, blk, 0, stream>>>(x, Wq, nullptr, nullptr, P, M, HID, HID);
    conv_silu_kernel<<<nconv, blk, 0, stream>>>(P, qcw, qcb, qb, 1.f);
    gemm_bt<2, true><<<g8, blk, 0, stream>>>(x, Wk, nullptr, nullptr, P, M, HID, HID);
    conv_silu_kernel<<<nconv, blk, 0, stream>>>(P, kcw, kcb, kb, 0.125f);
    gemm_bt<2, true><<<g8, blk, 0, stream>>>(x, Wv, nullptr, nullptr, P, M, HID, HID);
    conv_silu_kernel<<<nconv, blk, 0, stream>>>(P, vcw, vcb, vb, 1.f);
    gemm_bt<3, true><<<g8, blk, 0, stream>>>(x, Wa, ba, nullptr, P, M, HID, HID);
    gemm_bt<5, true><<<dim3(1, 32), blk, 0, stream>>>(x, Wb, bb, betab, nullptr, M, 16, HID);
    scan_kernel<<<128, dim3(64), 0, stream>>>(qb, kb, vb, P, betab, ob);
    gemm_bt<3, true><<<g8, blk, 0, stream>>>(x, Wg, nullptr, nullptr, qb, M, HID, HID);
    ln_gate_kernel<<<M * 16 / 4, blk, 0, stream>>>(ob, qb, lnw, lnb, kb);
  }

  gemm_bt<4, false><<<g8, blk, 0, stream>>>(kb, Wo, nullptr, outf, nullptr, M, HID, HID);
}

// Round 10
// 685.741 us; speedup vs baseline: 1.7651x; 1.2677x over previous
//
#include <hip/hip_runtime.h>
#include <hip/hip_bf16.h>
#include <cstdint>

// B=2, T=2048, HID=1024, H=16, DK=DV=64, K(conv)=4. fp32 in/out.
// ws: 4 bf16 planes (32 MB) [+ optional 5th plane xb if ws_size >= 40 MB].
// d_out as scratch: betab fp32 transposed [16][4096] at [0,256K); scan output
// plane ob bf16 at [8M,16M). Both dead before the final GEMM writes d_out.
// Scan: 256 blocks x 64 thr (1 block/CU); block owns 8 DV rows; 8 lanes/row;
// all-VALU 8-lane reductions: quad_perm xor1/xor2 + row_half_mirror (0x141)
// for the cross-quad combine (direction-free); deferred output reduce via LDS.

using bf16 = __hip_bfloat16;
typedef __bf16 bf16x8 __attribute__((ext_vector_type(8)));
typedef __bf16 bf16x4v __attribute__((ext_vector_type(4)));
typedef float f32x4 __attribute__((ext_vector_type(4)));
typedef float f32x2 __attribute__((ext_vector_type(2)));
typedef unsigned int u32x4 __attribute__((ext_vector_type(4)));

__device__ __forceinline__ __bf16 cvt_bf16(float f) {
  __hip_bfloat16 h = (__hip_bfloat16)f;
  return *reinterpret_cast<__bf16*>(&h);
}
__device__ __forceinline__ void async_copy16(const void* g, void* l) {
  __builtin_amdgcn_global_load_lds((const __attribute__((address_space(1))) void*)g,
                                   (__attribute__((address_space(3))) void*)l,
                                   16, 0, 0);
}
__device__ __forceinline__ float bcf(unsigned int u) { return __builtin_bit_cast(float, u); }
template <int CTRL>
__device__ __forceinline__ float dpp_f(float x) {
  int y = __builtin_amdgcn_update_dpp(0, __builtin_bit_cast(int, x), CTRL, 0xF, 0xF, true);
  return __builtin_bit_cast(float, y);
}

// fp32 -> bf16 plane (4M elements)
__global__ __launch_bounds__(256) void cvt_plane_kernel(
    const float* __restrict__ in, bf16* __restrict__ out)
{
  size_t i = ((size_t)blockIdx.x * 256 + threadIdx.x) * 4;
  float4 f = *(const float4*)(in + i);
  bf16x4v t;
  t[0] = cvt_bf16(f.x); t[1] = cvt_bf16(f.y); t[2] = cvt_bf16(f.z); t[3] = cvt_bf16(f.w);
  *(bf16x4v*)((__bf16*)out + i) = t;
}

// C = A * Bt^T. A: MxK (bf16 async-staged unless A_FP32); Bt: NxK fp32.
// MODE 2: raw->bf16; 3: sigmoid(acc+bias)->bf16; 4: raw->fp32; 5: sigmoid(acc+bias)->fp32 TRANSPOSED
template <int MODE, bool A_FP32>
__global__ __launch_bounds__(256) void gemm_bt(
    const void* __restrict__ Av, const float* __restrict__ Bt,
    const float* __restrict__ bias, float* __restrict__ Cf, bf16* __restrict__ Cb,
    int M, int N, int K)
{
  __shared__ __align__(16) __bf16 As[128 * 32];
  __shared__ __align__(16) __bf16 Bs[128 * 32];

  const int tid  = threadIdx.x;
  const int lane = tid & 63;
  const int wave = tid >> 6;
  const int tile_m = blockIdx.y * 128;
  const int tile_n = blockIdx.x * 128;
  const int wm = (wave >> 1) * 64;
  const int wn = (wave & 1) * 64;

  const int srow = lane >> 2;
  const int scol = (lane & 3) * 8;

  f32x4 acc[4][4];
#pragma unroll
  for (int i = 0; i < 4; ++i)
#pragma unroll
    for (int j = 0; j < 4; ++j) acc[i][j] = {0.f, 0.f, 0.f, 0.f};

  for (int k0 = 0; k0 < K; k0 += 32) {
    float4 b0[2], b1[2], a0[2], a1[2];
#pragma unroll
    for (int s = 0; s < 2; ++s) {
      int brow = tile_n + s * 64 + wave * 16 + srow;
      if (brow > N - 1) brow = N - 1;             // clamp (beta GEMM: N=16)
      const float* bp = Bt + (size_t)brow * K + k0 + scol;
      b0[s] = *(const float4*)bp;
      b1[s] = *(const float4*)(bp + 4);
      if (A_FP32) {
        int arow = tile_m + s * 64 + wave * 16 + srow;
        const float* ap = (const float*)Av + (size_t)arow * K + k0 + scol;
        a0[s] = *(const float4*)ap;
        a1[s] = *(const float4*)(ap + 4);
      }
    }
    __syncthreads();
#pragma unroll
    for (int s = 0; s < 2; ++s) {
      if (!A_FP32) {
        int arow = tile_m + s * 64 + wave * 16 + srow;
        async_copy16((const __bf16*)Av + (size_t)arow * K + k0 + scol,
                     &As[(s * 64 + wave * 16 + srow) * 32 + scol]);
      } else {
        bf16x8 ua;
        ua[0] = cvt_bf16(a0[s].x); ua[1] = cvt_bf16(a0[s].y);
        ua[2] = cvt_bf16(a0[s].z); ua[3] = cvt_bf16(a0[s].w);
        ua[4] = cvt_bf16(a1[s].x); ua[5] = cvt_bf16(a1[s].y);
        ua[6] = cvt_bf16(a1[s].z); ua[7] = cvt_bf16(a1[s].w);
        *(bf16x8*)&As[(s * 64 + wave * 16 + srow) * 32 + scol] = ua;
      }
      bf16x8 u;
      u[0] = cvt_bf16(b0[s].x); u[1] = cvt_bf16(b0[s].y);
      u[2] = cvt_bf16(b0[s].z); u[3] = cvt_bf16(b0[s].w);
      u[4] = cvt_bf16(b1[s].x); u[5] = cvt_bf16(b1[s].y);
      u[6] = cvt_bf16(b1[s].z); u[7] = cvt_bf16(b1[s].w);
      *(bf16x8*)&Bs[(s * 64 + wave * 16 + srow) * 32 + scol] = u;
    }
    __syncthreads();

    bf16x8 af[4], bfr[4];
#pragma unroll
    for (int i = 0; i < 4; ++i)
      af[i] = *(const bf16x8*)&As[(wm + i * 16 + (lane & 15)) * 32 + (lane >> 4) * 8];
#pragma unroll
    for (int j = 0; j < 4; ++j)
      bfr[j] = *(const bf16x8*)&Bs[(wn + j * 16 + (lane & 15)) * 32 + (lane >> 4) * 8];

#pragma unroll
    for (int i = 0; i < 4; ++i)
#pragma unroll
      for (int j = 0; j < 4; ++j)
        acc[i][j] = __builtin_amdgcn_mfma_f32_16x16x32_bf16(af[i], bfr[j], acc[i][j], 0, 0, 0);
  }

  // C/D layout (m89-verified): col = lane&15, row = (lane>>4)*4 + reg
#pragma unroll
  for (int i = 0; i < 4; ++i) {
#pragma unroll
    for (int j = 0; j < 4; ++j) {
#pragma unroll
      for (int r = 0; r < 4; ++r) {
        int gm = tile_m + wm + i * 16 + (lane >> 4) * 4 + r;
        int gn = tile_n + wn + j * 16 + (lane & 15);
        if (gn < N) {
          float val = acc[i][j][r];
          if (MODE == 3 || MODE == 5) {
            float bv = bias ? bias[gn] : 0.f;
            val = 1.f / (1.f + __expf(-(val + bv)));
          }
          if (MODE == 4)      Cf[(size_t)gm * N + gn] = val;
          else if (MODE == 5) Cf[(size_t)gn * M + gm] = val;   // transposed
          else                Cb[(size_t)gm * N + gn] = (bf16)val;
        }
      }
    }
  }
}

// causal depthwise conv K=4 + bias + SiLU (+scale). z: [B*T,1024] bf16 plane.
__global__ __launch_bounds__(256) void conv_silu_kernel(
    const bf16* __restrict__ z, const float* __restrict__ w,
    const float* __restrict__ bias, bf16* __restrict__ out, float scale)
{
  int idx = blockIdx.x * 256 + threadIdx.x;
  int c = idx & 1023;
  int m = idx >> 10;
  int t = m & 2047;
  float w0 = w[c * 4 + 0], w1 = w[c * 4 + 1], w2 = w[c * 4 + 2], w3 = w[c * 4 + 3];
  float acc = bias[c] + (float)z[idx] * w3;
  if (t >= 1) acc += (float)z[idx - 1024] * w2;
  if (t >= 2) acc += (float)z[idx - 2048] * w1;
  if (t >= 3) acc += (float)z[idx - 3072] * w0;
  float s = acc / (1.f + __expf(-acc));
  out[idx] = (bf16)(s * scale);
}

// delta-rule scan: 256 blocks (b,h,qd) x 64 thr; block owns DV rows
// [qd*8, qd*8+8). Lane (r8=lane>>3, sg=lane&7) holds S[r8][sg*8..+8) fp32.
__global__ __launch_bounds__(64) void scan_kernel(
    const bf16* __restrict__ q, const bf16* __restrict__ k,
    const bf16* __restrict__ v, const bf16* __restrict__ a,
    const float* __restrict__ betab, bf16* __restrict__ o)
{
  const int blk = blockIdx.x;
  const int qd = blk >> 5;           // DV slice 0..7
  const int bh = blk & 31;
  const int b = bh >> 4, h = bh & 15;
  const int lane = threadIdx.x;      // single wave
  const int r8 = lane >> 3;          // local row 0..7
  const int sg = lane & 7;
  const int c0 = sg * 8;

  __shared__ __align__(16) __bf16 sk[2][16][64];     // 4 KB
  __shared__ __align__(16) __bf16 sq[2][16][64];     // 4 KB
  __shared__ __align__(16) __bf16 sva[2][2][16][8];  // 1 KB [buf][v/a][step][row]
  __shared__ __align__(16) float  so[16][64];        // 4 KB per-step partials
  __shared__ __align__(16) __bf16 so2[16][8];        // reduced outputs
  __shared__ float sbeta[2048];                      // 8 KB

  {
    const float* bp = betab + (size_t)h * 4096 + b * 2048;
    for (int t = lane; t < 2048; t += 64) sbeta[t] = bp[t];
  }

  const size_t bkq = (size_t)b * 2048 * 1024 + h * 64;   // k/q plane base
  const size_t bva = bkq + qd * 8;                       // v/a/o slice base
  const __bf16* kp = (const __bf16*)k;
  const __bf16* qp = (const __bf16*)q;

  const int g_st = lane >> 3;          // staging row 0..7
  const int g_cg = (lane & 7) * 8;     // staging col
  const int va_vh = (lane >> 4) & 1;   // lanes 0-15: v, 16-31: a
  const int va_st = lane & 15;

  bf16x8 pk[2], pq[2], pva;
  auto fetch = [&](int t0) {
#pragma unroll
    for (int j = 0; j < 2; ++j) {
      int st = t0 + j * 8 + g_st;
      pk[j] = *(const bf16x8*)(kp + bkq + (size_t)st * 1024 + g_cg);
      pq[j] = *(const bf16x8*)(qp + bkq + (size_t)st * 1024 + g_cg);
    }
    if (lane < 32) {
      const __bf16* src = va_vh ? (const __bf16*)a : (const __bf16*)v;
      pva = *(const bf16x8*)(src + bva + (size_t)(t0 + va_st) * 1024);
    }
  };
  auto commit = [&](int cb) {
#pragma unroll
    for (int j = 0; j < 2; ++j) {
      *(bf16x8*)(&sk[cb][0][0] + j * 512 + (size_t)lane * 8) = pk[j];
      *(bf16x8*)(&sq[cb][0][0] + j * 512 + (size_t)lane * 8) = pq[j];
    }
    if (lane < 32) *(bf16x8*)(&sva[cb][va_vh][va_st][0]) = pva;
  };

  fetch(0); commit(0);

  f32x2 S2[4];
#pragma unroll
  for (int j = 0; j < 4; ++j) S2[j] = {0.f, 0.f};
  __syncthreads();

  for (int c = 0; c < 128; ++c) {
    const int buf = c & 1;
    const bool hasNext = (c + 1 < 128);
    if (hasNext) fetch((c + 1) * 16);   // global loads in flight during compute

    // 1-step register pipeline
    bf16x8 kk8[2], qq8[2];
    float vr2[2], ar2[2], bt2[2];
    kk8[0] = *(const bf16x8*)&sk[buf][0][c0];
    qq8[0] = *(const bf16x8*)&sq[buf][0][c0];
    vr2[0] = (float)sva[buf][0][0][r8];
    ar2[0] = (float)sva[buf][1][0][r8];
    bt2[0] = sbeta[c * 16];

#pragma unroll
    for (int i = 0; i < 16; ++i) {
      const int p = i & 1;
      if (i + 1 < 16) {
        kk8[p ^ 1] = *(const bf16x8*)&sk[buf][i + 1][c0];
        qq8[p ^ 1] = *(const bf16x8*)&sq[buf][i + 1][c0];
        vr2[p ^ 1] = (float)sva[buf][0][i + 1][r8];
        ar2[p ^ 1] = (float)sva[buf][1][i + 1][r8];
        bt2[p ^ 1] = sbeta[c * 16 + i + 1];
      }

      u32x4 kd = __builtin_bit_cast(u32x4, kk8[p]);
      u32x4 qd4 = __builtin_bit_cast(u32x4, qq8[p]);
      f32x2 k2[4], q2[4];
#pragma unroll
      for (int j = 0; j < 4; ++j) {
        k2[j] = {bcf(kd[j] << 16), bcf(kd[j] & 0xffff0000u)};
        q2[j] = {bcf(qd4[j] << 16), bcf(qd4[j] & 0xffff0000u)};
      }
      const float vr = vr2[p], ar = ar2[p], bt = bt2[p];

      f32x2 dd0 = S2[0] * k2[0];
      f32x2 dd1 = S2[1] * k2[1];
      dd0 += S2[2] * k2[2];
      dd1 += S2[3] * k2[3];
      f32x2 de = dd0 + dd1;
      float dot = de[0] + de[1];
      // 8-lane all-VALU reduction: xor1, xor2 (quad_perm), then cross-quad via
      // row_half_mirror (lane i <-> i^7 within 8-group; after xor1/xor2 every
      // lane of a quad holds the quad-sum, so the mirrored lane is always the
      // sibling quad's sum -- direction-free).
      dot += dpp_f<0xB1>(dot);
      dot += dpp_f<0x4E>(dot);
      dot += dpp_f<0x141>(dot);
      float cc = bt * (dot - vr);        // beta * err[row]

      const f32x2 cc2 = {cc, cc}, arv = {ar, ar};
      f32x2 oo0, oo1;
      {
        f32x2 t0 = cc2 * k2[0]; S2[0] = arv * S2[0] - t0; oo0 = S2[0] * q2[0];
        f32x2 t1 = cc2 * k2[1]; S2[1] = arv * S2[1] - t1; oo1 = S2[1] * q2[1];
        f32x2 t2 = cc2 * k2[2]; S2[2] = arv * S2[2] - t2; oo0 += S2[2] * q2[2];
        f32x2 t3 = cc2 * k2[3]; S2[3] = arv * S2[3] - t3; oo1 += S2[3] * q2[3];
      }
      f32x2 oe = oo0 + oo1;
      so[i][lane] = oe[0] + oe[1];       // deferred output partial (no reduce here)
    }

    // deferred output reduction + coalesced store (single wave: ds-ordered)
#pragma unroll
    for (int tk = 0; tk < 2; ++tk) {
      int task = lane + tk * 64;
      int st = task >> 3, rr = task & 7;
      float4 A = *(const float4*)&so[st][rr * 8];
      float4 Bv = *(const float4*)&so[st][rr * 8 + 4];
      float s = ((A.x + A.y) + (A.z + A.w)) + ((Bv.x + Bv.y) + (Bv.z + Bv.w));
      so2[st][rr] = cvt_bf16(s);
    }
    if (lane < 16)
      *(bf16x8*)((__bf16*)o + bva + (size_t)(c * 16 + lane) * 1024) =
          *(const bf16x8*)&so2[lane][0];

    if (hasNext) commit(buf ^ 1);
    __syncthreads();
  }
}

// LayerNorm over DV=64 per (b,t,h) row, *ln_w+ln_b, *gate -> bf16
__global__ __launch_bounds__(256) void ln_gate_kernel(
    const bf16* __restrict__ o, const bf16* __restrict__ g,
    const float* __restrict__ lnw, const float* __restrict__ lnb,
    bf16* __restrict__ out)
{
  int row = blockIdx.x * 4 + (threadIdx.x >> 6);
  int lane = threadIdx.x & 63;
  size_t idx = (size_t)row * 64 + lane;
  float xv = (float)o[idx];
  float mu = xv;
#pragma unroll
  for (int s = 1; s < 64; s <<= 1) mu += __shfl_xor(mu, s);
  mu *= (1.f / 64.f);
  float d = xv - mu;
  float vv = d * d;
#pragma unroll
  for (int s = 1; s < 64; s <<= 1) vv += __shfl_xor(vv, s);
  vv *= (1.f / 64.f);
  float y = d * rsqrtf(vv + 1e-5f) * lnw[lane] + lnb[lane];
  y *= (float)g[idx];
  out[idx] = (bf16)y;
}

extern "C" void kernel_launch(void* const* d_in, const int* in_sizes, int n_in,
                              void* d_out, int out_size, void* d_ws, size_t ws_size,
                              hipStream_t stream)
{
  const float* x   = (const float*)d_in[0];
  const float* Wq  = (const float*)d_in[1];
  const float* Wk  = (const float*)d_in[2];
  const float* Wv  = (const float*)d_in[3];
  const float* Wa  = (const float*)d_in[4];
  const float* ba  = (const float*)d_in[5];
  const float* Wb  = (const float*)d_in[6];
  const float* bb  = (const float*)d_in[7];
  const float* Wg  = (const float*)d_in[8];
  const float* Wo  = (const float*)d_in[9];
  const float* qcw = (const float*)d_in[10];
  const float* qcb = (const float*)d_in[11];
  const float* kcw = (const float*)d_in[12];
  const float* kcb = (const float*)d_in[13];
  const float* vcw = (const float*)d_in[14];
  const float* vcb = (const float*)d_in[15];
  const float* lnw = (const float*)d_in[16];
  const float* lnb = (const float*)d_in[17];

  const int M = 4096, HID = 1024;
  const size_t PLANE = (size_t)M * HID;
  const size_t PB = PLANE * sizeof(bf16);          // 8 MB bf16 plane

  char* ws = (char*)d_ws;
  bf16* P  = (bf16*)(ws);            // z-plane x3, then a-gate
  bf16* qb = (bf16*)(ws + PB);       // q, then g-gate
  bf16* kb = (bf16*)(ws + 2 * PB);   // k, then normalized*gated o
  bf16* vb = (bf16*)(ws + 3 * PB);   // v

  // d_out scratch: betab transposed fp32 [16][4096] at [0,256K); ob at [8M,16M)
  float* outf  = (float*)d_out;
  float* betab = outf;
  bf16*  ob    = (bf16*)((char*)d_out + 8 * 1024 * 1024);

  const bool rich = (ws_size >= 5 * PB + 1024);
  bf16* xb = rich ? (bf16*)(ws + 4 * PB) : nullptr;

  dim3 blk(256);
  dim3 g8(8, 32);
  int nconv = (int)(PLANE / 256);

  if (rich) {
    cvt_plane_kernel<<<(int)(PLANE / 1024), blk, 0, stream>>>(x, xb);
    gemm_bt<2, false><<<g8, blk, 0, stream>>>(xb, Wq, nullptr, nullptr, P, M, HID, HID);
    conv_silu_kernel<<<nconv, blk, 0, stream>>>(P, qcw, qcb, qb, 1.f);
    gemm_bt<2, false><<<g8, blk, 0, stream>>>(xb, Wk, nullptr, nullptr, P, M, HID, HID);
    conv_silu_kernel<<<nconv, blk, 0, stream>>>(P, kcw, kcb, kb, 0.125f);
    gemm_bt<2, false><<<g8, blk, 0, stream>>>(xb, Wv, nullptr, nullptr, P, M, HID, HID);
    conv_silu_kernel<<<nconv, blk, 0, stream>>>(P, vcw, vcb, vb, 1.f);
    gemm_bt<3, false><<<g8, blk, 0, stream>>>(xb, Wa, ba, nullptr, P, M, HID, HID);
    gemm_bt<5, false><<<dim3(1, 32), blk, 0, stream>>>(xb, Wb, bb, betab, nullptr, M, 16, HID);
    scan_kernel<<<256, dim3(64), 0, stream>>>(qb, kb, vb, P, betab, ob);
    gemm_bt<3, false><<<g8, blk, 0, stream>>>(xb, Wg, nullptr, nullptr, qb, M, HID, HID);
    ln_gate_kernel<<<M * 16 / 4, blk, 0, stream>>>(ob, qb, lnw, lnb, kb);
  } else {
    gemm_bt<2, true><<<g8, blk, 0, stream>>>(x, Wq, nullptr, nullptr, P, M, HID, HID);
    conv_silu_kernel<<<nconv, blk, 0, stream>>>(P, qcw, qcb, qb, 1.f);
    gemm_bt<2, true><<<g8, blk, 0, stream>>>(x, Wk, nullptr, nullptr, P, M, HID, HID);
    conv_silu_kernel<<<nconv, blk, 0, stream>>>(P, kcw, kcb, kb, 0.125f);
    gemm_bt<2, true><<<g8, blk, 0, stream>>>(x, Wv, nullptr, nullptr, P, M, HID, HID);
    conv_silu_kernel<<<nconv, blk, 0, stream>>>(P, vcw, vcb, vb, 1.f);
    gemm_bt<3, true><<<g8, blk, 0, stream>>>(x, Wa, ba, nullptr, P, M, HID, HID);
    gemm_bt<5, true><<<dim3(1, 32), blk, 0, stream>>>(x, Wb, bb, betab, nullptr, M, 16, HID);
    scan_kernel<<<256, dim3(64), 0, stream>>>(qb, kb, vb, P, betab, ob);
    gemm_bt<3, true><<<g8, blk, 0, stream>>>(x, Wg, nullptr, nullptr, qb, M, HID, HID);
    ln_gate_kernel<<<M * 16 / 4, blk, 0, stream>>>(ob, qb, lnw, lnb, kb);
  }

  gemm_bt<4, false><<<g8, blk, 0, stream>>>(kb, Wo, nullptr, outf, nullptr, M, HID, HID);
}

// Round 11
// 634.049 us; speedup vs baseline: 1.9090x; 1.0815x over previous
//
#include <hip/hip_runtime.h>
#include <hip/hip_bf16.h>
#include <cstdint>

// B=2, T=2048, HID=1024, H=16, DK=DV=64, K(conv)=4. fp32 in/out.
// ws: 4 bf16 planes (32 MB) [+ optional 5th plane xb if ws_size >= 40 MB].
// d_out as scratch: betab fp32 transposed [16][4096] at [0,256K); scan output
// plane ob bf16 at [8M,16M). Both dead before the final GEMM writes d_out.
// Scan: 512 blocks x 64 thr (2 blocks/CU); block owns 4 DV rows; 16 lanes/row;
// all-VALU 16-lane reductions: quad_perm xor1/xor2 + row_half_mirror(0x141) +
// row_mirror(0x140) -- all direction-free; deferred output reduce via LDS.

using bf16 = __hip_bfloat16;
typedef __bf16 bf16x8 __attribute__((ext_vector_type(8)));
typedef __bf16 bf16x4v __attribute__((ext_vector_type(4)));
typedef float f32x4 __attribute__((ext_vector_type(4)));
typedef float f32x2 __attribute__((ext_vector_type(2)));
typedef unsigned int u32x4 __attribute__((ext_vector_type(4)));
typedef unsigned int u32x2 __attribute__((ext_vector_type(2)));

__device__ __forceinline__ __bf16 cvt_bf16(float f) {
  __hip_bfloat16 h = (__hip_bfloat16)f;
  return *reinterpret_cast<__bf16*>(&h);
}
__device__ __forceinline__ void async_copy16(const void* g, void* l) {
  __builtin_amdgcn_global_load_lds((const __attribute__((address_space(1))) void*)g,
                                   (__attribute__((address_space(3))) void*)l,
                                   16, 0, 0);
}
__device__ __forceinline__ float bcf(unsigned int u) { return __builtin_bit_cast(float, u); }
template <int CTRL>
__device__ __forceinline__ float dpp_f(float x) {
  int y = __builtin_amdgcn_update_dpp(0, __builtin_bit_cast(int, x), CTRL, 0xF, 0xF, true);
  return __builtin_bit_cast(float, y);
}

// fp32 -> bf16 plane (4M elements)
__global__ __launch_bounds__(256) void cvt_plane_kernel(
    const float* __restrict__ in, bf16* __restrict__ out)
{
  size_t i = ((size_t)blockIdx.x * 256 + threadIdx.x) * 4;
  float4 f = *(const float4*)(in + i);
  bf16x4v t;
  t[0] = cvt_bf16(f.x); t[1] = cvt_bf16(f.y); t[2] = cvt_bf16(f.z); t[3] = cvt_bf16(f.w);
  *(bf16x4v*)((__bf16*)out + i) = t;
}

// C = A * Bt^T. A: MxK (bf16 async-staged unless A_FP32); Bt: NxK fp32.
// MODE 2: raw->bf16; 3: sigmoid(acc+bias)->bf16; 4: raw->fp32; 5: sigmoid(acc+bias)->fp32 TRANSPOSED
template <int MODE, bool A_FP32>
__global__ __launch_bounds__(256) void gemm_bt(
    const void* __restrict__ Av, const float* __restrict__ Bt,
    const float* __restrict__ bias, float* __restrict__ Cf, bf16* __restrict__ Cb,
    int M, int N, int K)
{
  __shared__ __align__(16) __bf16 As[128 * 32];
  __shared__ __align__(16) __bf16 Bs[128 * 32];

  const int tid  = threadIdx.x;
  const int lane = tid & 63;
  const int wave = tid >> 6;
  const int tile_m = blockIdx.y * 128;
  const int tile_n = blockIdx.x * 128;
  const int wm = (wave >> 1) * 64;
  const int wn = (wave & 1) * 64;

  const int srow = lane >> 2;
  const int scol = (lane & 3) * 8;

  f32x4 acc[4][4];
#pragma unroll
  for (int i = 0; i < 4; ++i)
#pragma unroll
    for (int j = 0; j < 4; ++j) acc[i][j] = {0.f, 0.f, 0.f, 0.f};

  for (int k0 = 0; k0 < K; k0 += 32) {
    float4 b0[2], b1[2], a0[2], a1[2];
#pragma unroll
    for (int s = 0; s < 2; ++s) {
      int brow = tile_n + s * 64 + wave * 16 + srow;
      if (brow > N - 1) brow = N - 1;             // clamp (beta GEMM: N=16)
      const float* bp = Bt + (size_t)brow * K + k0 + scol;
      b0[s] = *(const float4*)bp;
      b1[s] = *(const float4*)(bp + 4);
      if (A_FP32) {
        int arow = tile_m + s * 64 + wave * 16 + srow;
        const float* ap = (const float*)Av + (size_t)arow * K + k0 + scol;
        a0[s] = *(const float4*)ap;
        a1[s] = *(const float4*)(ap + 4);
      }
    }
    __syncthreads();
#pragma unroll
    for (int s = 0; s < 2; ++s) {
      if (!A_FP32) {
        int arow = tile_m + s * 64 + wave * 16 + srow;
        async_copy16((const __bf16*)Av + (size_t)arow * K + k0 + scol,
                     &As[(s * 64 + wave * 16 + srow) * 32 + scol]);
      } else {
        bf16x8 ua;
        ua[0] = cvt_bf16(a0[s].x); ua[1] = cvt_bf16(a0[s].y);
        ua[2] = cvt_bf16(a0[s].z); ua[3] = cvt_bf16(a0[s].w);
        ua[4] = cvt_bf16(a1[s].x); ua[5] = cvt_bf16(a1[s].y);
        ua[6] = cvt_bf16(a1[s].z); ua[7] = cvt_bf16(a1[s].w);
        *(bf16x8*)&As[(s * 64 + wave * 16 + srow) * 32 + scol] = ua;
      }
      bf16x8 u;
      u[0] = cvt_bf16(b0[s].x); u[1] = cvt_bf16(b0[s].y);
      u[2] = cvt_bf16(b0[s].z); u[3] = cvt_bf16(b0[s].w);
      u[4] = cvt_bf16(b1[s].x); u[5] = cvt_bf16(b1[s].y);
      u[6] = cvt_bf16(b1[s].z); u[7] = cvt_bf16(b1[s].w);
      *(bf16x8*)&Bs[(s * 64 + wave * 16 + srow) * 32 + scol] = u;
    }
    __syncthreads();

    bf16x8 af[4], bfr[4];
#pragma unroll
    for (int i = 0; i < 4; ++i)
      af[i] = *(const bf16x8*)&As[(wm + i * 16 + (lane & 15)) * 32 + (lane >> 4) * 8];
#pragma unroll
    for (int j = 0; j < 4; ++j)
      bfr[j] = *(const bf16x8*)&Bs[(wn + j * 16 + (lane & 15)) * 32 + (lane >> 4) * 8];

#pragma unroll
    for (int i = 0; i < 4; ++i)
#pragma unroll
      for (int j = 0; j < 4; ++j)
        acc[i][j] = __builtin_amdgcn_mfma_f32_16x16x32_bf16(af[i], bfr[j], acc[i][j], 0, 0, 0);
  }

  // C/D layout (m89-verified): col = lane&15, row = (lane>>4)*4 + reg
#pragma unroll
  for (int i = 0; i < 4; ++i) {
#pragma unroll
    for (int j = 0; j < 4; ++j) {
#pragma unroll
      for (int r = 0; r < 4; ++r) {
        int gm = tile_m + wm + i * 16 + (lane >> 4) * 4 + r;
        int gn = tile_n + wn + j * 16 + (lane & 15);
        if (gn < N) {
          float val = acc[i][j][r];
          if (MODE == 3 || MODE == 5) {
            float bv = bias ? bias[gn] : 0.f;
            val = 1.f / (1.f + __expf(-(val + bv)));
          }
          if (MODE == 4)      Cf[(size_t)gm * N + gn] = val;
          else if (MODE == 5) Cf[(size_t)gn * M + gm] = val;   // transposed
          else                Cb[(size_t)gm * N + gn] = (bf16)val;
        }
      }
    }
  }
}

// causal depthwise conv K=4 + bias + SiLU (+scale). z: [B*T,1024] bf16 plane.
__global__ __launch_bounds__(256) void conv_silu_kernel(
    const bf16* __restrict__ z, const float* __restrict__ w,
    const float* __restrict__ bias, bf16* __restrict__ out, float scale)
{
  int idx = blockIdx.x * 256 + threadIdx.x;
  int c = idx & 1023;
  int m = idx >> 10;
  int t = m & 2047;
  float w0 = w[c * 4 + 0], w1 = w[c * 4 + 1], w2 = w[c * 4 + 2], w3 = w[c * 4 + 3];
  float acc = bias[c] + (float)z[idx] * w3;
  if (t >= 1) acc += (float)z[idx - 1024] * w2;
  if (t >= 2) acc += (float)z[idx - 2048] * w1;
  if (t >= 3) acc += (float)z[idx - 3072] * w0;
  float s = acc / (1.f + __expf(-acc));
  out[idx] = (bf16)(s * scale);
}

// delta-rule scan: 512 blocks (b,h,qd) x 64 thr; block owns DV rows
// [qd*4, qd*4+4). Lane (r4=lane>>4, sg=lane&15) holds S[r4][sg*4..+4) fp32.
// blk = qd*32 + bh => blk%8 = bh%8 => all 16 siblings of a (b,h) on one XCD.
__global__ __launch_bounds__(64) void scan_kernel(
    const bf16* __restrict__ q, const bf16* __restrict__ k,
    const bf16* __restrict__ v, const bf16* __restrict__ a,
    const float* __restrict__ betab, bf16* __restrict__ o)
{
  const int blk = blockIdx.x;
  const int qd = blk >> 5;           // DV slice 0..15 (4 rows each)
  const int bh = blk & 31;
  const int b = bh >> 4, h = bh & 15;
  const int lane = threadIdx.x;      // single wave
  const int r4 = lane >> 4;          // local row 0..3
  const int sg = lane & 15;
  const int c0 = sg * 4;             // bf16 col offset

  __shared__ __align__(16) __bf16 sk[2][16][64];     // 4 KB
  __shared__ __align__(16) __bf16 sq[2][16][64];     // 4 KB
  __shared__ __align__(16) __bf16 sva[2][2][16][4];  // 512 B [buf][v/a][step][row]
  __shared__ __align__(16) float  so[16][64];        // 4 KB per-step partials
  __shared__ __align__(16) __bf16 so2[16][4];        // reduced outputs
  __shared__ float sbeta[2048];                      // 8 KB

  {
    const float* bp = betab + (size_t)h * 4096 + b * 2048;
    for (int t = lane; t < 2048; t += 64) sbeta[t] = bp[t];
  }

  const size_t bkq = (size_t)b * 2048 * 1024 + h * 64;   // k/q plane base
  const size_t bva = bkq + qd * 4;                       // v/a/o slice base
  const __bf16* kp = (const __bf16*)k;
  const __bf16* qp = (const __bf16*)q;

  const int g_st = lane >> 3;          // staging row 0..7
  const int g_cg = (lane & 7) * 8;     // staging col
  const int va_vh = (lane >> 4) & 1;   // lanes 0-15: v, 16-31: a
  const int va_st = lane & 15;

  bf16x8 pk[2], pq[2];
  bf16x4v pva;
  auto fetch = [&](int t0) {
#pragma unroll
    for (int j = 0; j < 2; ++j) {
      int st = t0 + j * 8 + g_st;
      pk[j] = *(const bf16x8*)(kp + bkq + (size_t)st * 1024 + g_cg);
      pq[j] = *(const bf16x8*)(qp + bkq + (size_t)st * 1024 + g_cg);
    }
    if (lane < 32) {
      const __bf16* src = va_vh ? (const __bf16*)a : (const __bf16*)v;
      pva = *(const bf16x4v*)(src + bva + (size_t)(t0 + va_st) * 1024);
    }
  };
  auto commit = [&](int cb) {
#pragma unroll
    for (int j = 0; j < 2; ++j) {
      *(bf16x8*)(&sk[cb][0][0] + j * 512 + (size_t)lane * 8) = pk[j];
      *(bf16x8*)(&sq[cb][0][0] + j * 512 + (size_t)lane * 8) = pq[j];
    }
    if (lane < 32) *(bf16x4v*)(&sva[cb][va_vh][va_st][0]) = pva;
  };

  fetch(0); commit(0);

  f32x2 S2[2];
  S2[0] = {0.f, 0.f}; S2[1] = {0.f, 0.f};
  __syncthreads();

  for (int c = 0; c < 128; ++c) {
    const int buf = c & 1;
    const bool hasNext = (c + 1 < 128);
    if (hasNext) fetch((c + 1) * 16);   // global loads in flight during compute

    // 1-step register pipeline
    bf16x4v kk4[2], qq4[2];
    float vr2[2], ar2[2], bt2[2];
    kk4[0] = *(const bf16x4v*)&sk[buf][0][c0];
    qq4[0] = *(const bf16x4v*)&sq[buf][0][c0];
    vr2[0] = (float)sva[buf][0][0][r4];
    ar2[0] = (float)sva[buf][1][0][r4];
    bt2[0] = sbeta[c * 16];

#pragma unroll
    for (int i = 0; i < 16; ++i) {
      const int p = i & 1;
      if (i + 1 < 16) {
        kk4[p ^ 1] = *(const bf16x4v*)&sk[buf][i + 1][c0];
        qq4[p ^ 1] = *(const bf16x4v*)&sq[buf][i + 1][c0];
        vr2[p ^ 1] = (float)sva[buf][0][i + 1][r4];
        ar2[p ^ 1] = (float)sva[buf][1][i + 1][r4];
        bt2[p ^ 1] = sbeta[c * 16 + i + 1];
      }

      u32x2 kd = __builtin_bit_cast(u32x2, kk4[p]);
      u32x2 qd2 = __builtin_bit_cast(u32x2, qq4[p]);
      f32x2 k2[2], q2[2];
#pragma unroll
      for (int j = 0; j < 2; ++j) {
        k2[j] = {bcf(kd[j] << 16), bcf(kd[j] & 0xffff0000u)};
        q2[j] = {bcf(qd2[j] << 16), bcf(qd2[j] & 0xffff0000u)};
      }
      const float vr = vr2[p], ar = ar2[p], bt = bt2[p];

      f32x2 dd = S2[0] * k2[0];
      dd += S2[1] * k2[1];
      float dot = dd[0] + dd[1];
      // 16-lane all-VALU reduction (direction-free): quad xor1, xor2, then
      // half-mirror (i^7: crosses quads within 8-group), row-mirror (i^15:
      // crosses 8-groups within the 16-lane DPP row).
      dot += dpp_f<0xB1>(dot);
      dot += dpp_f<0x4E>(dot);
      dot += dpp_f<0x141>(dot);
      dot += dpp_f<0x140>(dot);
      float cc = bt * (dot - vr);        // beta * err[row]

      const f32x2 cc2 = {cc, cc}, arv = {ar, ar};
      f32x2 oo;
      {
        f32x2 t0 = cc2 * k2[0]; S2[0] = arv * S2[0] - t0; oo = S2[0] * q2[0];
        f32x2 t1 = cc2 * k2[1]; S2[1] = arv * S2[1] - t1; oo += S2[1] * q2[1];
      }
      so[i][lane] = oo[0] + oo[1];       // deferred output partial (no reduce here)
    }

    // deferred output reduction + coalesced store (single wave: ds-ordered)
    {
      int st = lane >> 2, rr = lane & 3;      // 64 outputs: 16 steps x 4 rows
      float4 A0 = *(const float4*)&so[st][rr * 16];
      float4 A1 = *(const float4*)&so[st][rr * 16 + 4];
      float4 A2 = *(const float4*)&so[st][rr * 16 + 8];
      float4 A3 = *(const float4*)&so[st][rr * 16 + 12];
      float s = (((A0.x + A0.y) + (A0.z + A0.w)) + ((A1.x + A1.y) + (A1.z + A1.w)))
              + (((A2.x + A2.y) + (A2.z + A2.w)) + ((A3.x + A3.y) + (A3.z + A3.w)));
      so2[st][rr] = cvt_bf16(s);
    }
    if (lane < 16)
      *(bf16x4v*)((__bf16*)o + bva + (size_t)(c * 16 + lane) * 1024) =
          *(const bf16x4v*)&so2[lane][0];

    if (hasNext) commit(buf ^ 1);
    __syncthreads();
  }
}

// LayerNorm over DV=64 per (b,t,h) row, *ln_w+ln_b, *gate -> bf16
__global__ __launch_bounds__(256) void ln_gate_kernel(
    const bf16* __restrict__ o, const bf16* __restrict__ g,
    const float* __restrict__ lnw, const float* __restrict__ lnb,
    bf16* __restrict__ out)
{
  int row = blockIdx.x * 4 + (threadIdx.x >> 6);
  int lane = threadIdx.x & 63;
  size_t idx = (size_t)row * 64 + lane;
  float xv = (float)o[idx];
  float mu = xv;
#pragma unroll
  for (int s = 1; s < 64; s <<= 1) mu += __shfl_xor(mu, s);
  mu *= (1.f / 64.f);
  float d = xv - mu;
  float vv = d * d;
#pragma unroll
  for (int s = 1; s < 64; s <<= 1) vv += __shfl_xor(vv, s);
  vv *= (1.f / 64.f);
  float y = d * rsqrtf(vv + 1e-5f) * lnw[lane] + lnb[lane];
  y *= (float)g[idx];
  out[idx] = (bf16)y;
}

extern "C" void kernel_launch(void* const* d_in, const int* in_sizes, int n_in,
                              void* d_out, int out_size, void* d_ws, size_t ws_size,
                              hipStream_t stream)
{
  const float* x   = (const float*)d_in[0];
  const float* Wq  = (const float*)d_in[1];
  const float* Wk  = (const float*)d_in[2];
  const float* Wv  = (const float*)d_in[3];
  const float* Wa  = (const float*)d_in[4];
  const float* ba  = (const float*)d_in[5];
  const float* Wb  = (const float*)d_in[6];
  const float* bb  = (const float*)d_in[7];
  const float* Wg  = (const float*)d_in[8];
  const float* Wo  = (const float*)d_in[9];
  const float* qcw = (const float*)d_in[10];
  const float* qcb = (const float*)d_in[11];
  const float* kcw = (const float*)d_in[12];
  const float* kcb = (const float*)d_in[13];
  const float* vcw = (const float*)d_in[14];
  const float* vcb = (const float*)d_in[15];
  const float* lnw = (const float*)d_in[16];
  const float* lnb = (const float*)d_in[17];

  const int M = 4096, HID = 1024;
  const size_t PLANE = (size_t)M * HID;
  const size_t PB = PLANE * sizeof(bf16);          // 8 MB bf16 plane

  char* ws = (char*)d_ws;
  bf16* P  = (bf16*)(ws);            // z-plane x3, then a-gate
  bf16* qb = (bf16*)(ws + PB);       // q, then g-gate
  bf16* kb = (bf16*)(ws + 2 * PB);   // k, then normalized*gated o
  bf16* vb = (bf16*)(ws + 3 * PB);   // v

  // d_out scratch: betab transposed fp32 [16][4096] at [0,256K); ob at [8M,16M)
  float* outf  = (float*)d_out;
  float* betab = outf;
  bf16*  ob    = (bf16*)((char*)d_out + 8 * 1024 * 1024);

  const bool rich = (ws_size >= 5 * PB + 1024);
  bf16* xb = rich ? (bf16*)(ws + 4 * PB) : nullptr;

  dim3 blk(256);
  dim3 g8(8, 32);
  int nconv = (int)(PLANE / 256);

  if (rich) {
    cvt_plane_kernel<<<(int)(PLANE / 1024), blk, 0, stream>>>(x, xb);
    gemm_bt<2, false><<<g8, blk, 0, stream>>>(xb, Wq, nullptr, nullptr, P, M, HID, HID);
    conv_silu_kernel<<<nconv, blk, 0, stream>>>(P, qcw, qcb, qb, 1.f);
    gemm_bt<2, false><<<g8, blk, 0, stream>>>(xb, Wk, nullptr, nullptr, P, M, HID, HID);
    conv_silu_kernel<<<nconv, blk, 0, stream>>>(P, kcw, kcb, kb, 0.125f);
    gemm_bt<2, false><<<g8, blk, 0, stream>>>(xb, Wv, nullptr, nullptr, P, M, HID, HID);
    conv_silu_kernel<<<nconv, blk, 0, stream>>>(P, vcw, vcb, vb, 1.f);
    gemm_bt<3, false><<<g8, blk, 0, stream>>>(xb, Wa, ba, nullptr, P, M, HID, HID);
    gemm_bt<5, false><<<dim3(1, 32), blk, 0, stream>>>(xb, Wb, bb, betab, nullptr, M, 16, HID);
    scan_kernel<<<512, dim3(64), 0, stream>>>(qb, kb, vb, P, betab, ob);
    gemm_bt<3, false><<<g8, blk, 0, stream>>>(xb, Wg, nullptr, nullptr, qb, M, HID, HID);
    ln_gate_kernel<<<M * 16 / 4, blk, 0, stream>>>(ob, qb, lnw, lnb, kb);
  } else {
    gemm_bt<2, true><<<g8, blk, 0, stream>>>(x, Wq, nullptr, nullptr, P, M, HID, HID);
    conv_silu_kernel<<<nconv, blk, 0, stream>>>(P, qcw, qcb, qb, 1.f);
    gemm_bt<2, true><<<g8, blk, 0, stream>>>(x, Wk, nullptr, nullptr, P, M, HID, HID);
    conv_silu_kernel<<<nconv, blk, 0, stream>>>(P, kcw, kcb, kb, 0.125f);
    gemm_bt<2, true><<<g8, blk, 0, stream>>>(x, Wv, nullptr, nullptr, P, M, HID, HID);
    conv_silu_kernel<<<nconv, blk, 0, stream>>>(P, vcw, vcb, vb, 1.f);
    gemm_bt<3, true><<<g8, blk, 0, stream>>>(x, Wa, ba, nullptr, P, M, HID, HID);
    gemm_bt<5, true><<<dim3(1, 32), blk, 0, stream>>>(x, Wb, bb, betab, nullptr, M, 16, HID);
    scan_kernel<<<512, dim3(64), 0, stream>>>(qb, kb, vb, P, betab, ob);
    gemm_bt<3, true><<<g8, blk, 0, stream>>>(x, Wg, nullptr, nullptr, qb, M, HID, HID);
    ln_gate_kernel<<<M * 16 / 4, blk, 0, stream>>>(ob, qb, lnw, lnb, kb);
  }

  gemm_bt<4, false><<<g8, blk, 0, stream>>>(kb, Wo, nullptr, outf, nullptr, M, HID, HID);
}